// Round 18
// baseline (104.628 us; speedup 1.0000x reference)
//
#include <hip/hip_runtime.h>
#include <hip/hip_bf16.h>

#define NPAIR 4096
#define DIM   768            // fp8: 768 bytes per row
#define N2    8192
#define BM    128            // block rows (4 waves as 2x2, each 64x64)
#define BNB   128            // block cols per col-block
#define KBLK  64             // K tile bytes; 3 buffers x 16KB = 48KB LDS
#define KITER (DIM / KBLK)   // 12
#define NSTRIP 16            // grid.y
#define CPB   ((N2 / BNB) / NSTRIP)    // 4 col-blocks per strip
#define NBI   (N2 / BM)      // 64
#define TOT   (CPB * KITER)  // 48 K-tile iterations per block
#define SC1   0x7F7F7F7F     // packed E8M0 scales: all 1.0

constexpr float INV_T = 1.0f / 0.07f;  // also the fixed softmax max M

typedef float f32x16 __attribute__((ext_vector_type(16)));
typedef int   i32x8  __attribute__((ext_vector_type(8)));
#define AS1 __attribute__((address_space(1)))
#define AS3 __attribute__((address_space(3)))

// ---------------- normalize: one wave per row, fp32 in -> fp8 e4m3 out ------
__global__ void knorm(const float* __restrict__ z1, const float* __restrict__ z2,
                      unsigned char* __restrict__ zq) {
    const int row  = blockIdx.x * 4 + (threadIdx.x >> 6);
    const int lane = threadIdx.x & 63;
    const float* src = (row < NPAIR) ? (z1 + (size_t)row * DIM)
                                     : (z2 + (size_t)(row - NPAIR) * DIM);
    float4 v[3];
    float ss = 0.f;
#pragma unroll
    for (int i = 0; i < 3; ++i) {
        v[i] = reinterpret_cast<const float4*>(src)[lane + 64 * i];
        ss += v[i].x * v[i].x + v[i].y * v[i].y + v[i].z * v[i].z + v[i].w * v[i].w;
    }
#pragma unroll
    for (int off = 32; off; off >>= 1) ss += __shfl_xor(ss, off);
    const float scale = 1.0f / fmaxf(sqrtf(ss), 1e-12f);
    unsigned int* dst = reinterpret_cast<unsigned int*>(zq + (size_t)row * DIM);
#pragma unroll
    for (int i = 0; i < 3; ++i) {
        unsigned int u = 0;
        u = __builtin_amdgcn_cvt_pk_fp8_f32(v[i].x * scale, v[i].y * scale, u, false);
        u = __builtin_amdgcn_cvt_pk_fp8_f32(v[i].z * scale, v[i].w * scale, u, true);
        dst[lane + 64 * i] = u;
    }
}

// ---------------- positive-pair dots from fp8 (consistent with klse) --------
__global__ void kpos(const unsigned char* __restrict__ zq, float* __restrict__ pos) {
    const int pair = blockIdx.x * 4 + (threadIdx.x >> 6);
    const int lane = threadIdx.x & 63;
    const unsigned int* a = reinterpret_cast<const unsigned int*>(zq + (size_t)pair * DIM);
    const unsigned int* b = reinterpret_cast<const unsigned int*>(zq + (size_t)(pair + NPAIR) * DIM);
    float s = 0.f;
#pragma unroll
    for (int i = 0; i < 3; ++i) {
        const unsigned int ua = a[lane + 64 * i];
        const unsigned int ub = b[lane + 64 * i];
        s += __builtin_amdgcn_cvt_f32_fp8(ua, 0) * __builtin_amdgcn_cvt_f32_fp8(ub, 0);
        s += __builtin_amdgcn_cvt_f32_fp8(ua, 1) * __builtin_amdgcn_cvt_f32_fp8(ub, 1);
        s += __builtin_amdgcn_cvt_f32_fp8(ua, 2) * __builtin_amdgcn_cvt_f32_fp8(ub, 2);
        s += __builtin_amdgcn_cvt_f32_fp8(ua, 3) * __builtin_amdgcn_cvt_f32_fp8(ub, 3);
    }
#pragma unroll
    for (int off = 32; off; off >>= 1) s += __shfl_xor(s, off);
    if (lane == 0) pos[pair] = s * INV_T;
}

// ---------------- main: R16 engine + counted-vmcnt triple buffer ------------
// Per iter: vmcnt(4) waits only for loads issued TWO iters ago (never a
// fresh drain), one barrier, stage(it+2) into the third buffer, then
// 8 ds_read_b128 + 4 mfma_scale_f32_32x32x64_f8f6f4 (scales=1.0).
// Safety: top-of-iter barrier means all waves finished reading
// b[(it-1)%3] == b[(it+2)%3] before it is restaged. 48KB LDS -> 3 blocks/CU.
__global__ __launch_bounds__(256, 3) void klse(const unsigned char* __restrict__ zq,
                                               float* __restrict__ rowsum) {
    __shared__ __align__(16) unsigned char As[3][BM * KBLK / 2];   // 3 x 8 KB
    __shared__ __align__(16) unsigned char Bs[3][BM * KBLK / 2];   // 3 x 8 KB
    const int tid  = threadIdx.x;
    const int wave = tid >> 6;
    const int lane = tid & 63;
    const int wr = wave >> 1, wc = wave & 1;
    const int hi = lane >> 5, rlo = lane & 31;
    const int bi = blockIdx.x;
    const int rb = bi * BM;

    // ---- staging geometry (per-thread, loop-invariant) ----
    const int sr   = tid >> 2;                 // row within 64-row group
    const int soff = (((tid & 3) ^ ((sr >> 1) & 3)) << 4);  // swizzled src offset
    const size_t offA0 = (size_t)(rb + sr) * DIM + soff;
    const size_t offA1 = (size_t)(rb + 64 + sr) * DIM + soff;
    const size_t offB0 = (size_t)sr * DIM + soff;            // + c0*DIM at use
    const size_t offB1 = (size_t)(64 + sr) * DIM + soff;

    auto stage = [&](int c0, int koff, int buf) {
        __builtin_amdgcn_global_load_lds(
            (const AS1 unsigned int*)(zq + offA0 + koff),
            (AS3 unsigned int*)(&As[buf][tid * 16]), 16, 0, 0);
        __builtin_amdgcn_global_load_lds(
            (const AS1 unsigned int*)(zq + offA1 + koff),
            (AS3 unsigned int*)(&As[buf][4096 + tid * 16]), 16, 0, 0);
        __builtin_amdgcn_global_load_lds(
            (const AS1 unsigned int*)(zq + (size_t)c0 * DIM + offB0 + koff),
            (AS3 unsigned int*)(&Bs[buf][tid * 16]), 16, 0, 0);
        __builtin_amdgcn_global_load_lds(
            (const AS1 unsigned int*)(zq + (size_t)c0 * DIM + offB1 + koff),
            (AS3 unsigned int*)(&Bs[buf][4096 + tid * 16]), 16, 0, 0);
    };

    // ---- fragment-read geometry (constant per iter) ----
    const int sw  = (rlo >> 1) & 3;
    const int pg0 = ((2 * hi) ^ sw) << 4;      // first b128 (16B granule)
    const int pg1 = ((2 * hi + 1) ^ sw) << 4;  // second b128
    const int raA = (wr * 64 + rlo) * KBLK;
    const int raB = raA + 32 * KBLK;
    const int caA = (wc * 64 + rlo) * KBLK;
    const int caB = caA + 32 * KBLK;

    auto ldf = [&](const unsigned char* p) -> i32x8 {
        int4 u = *reinterpret_cast<const int4*>(p + pg0);
        int4 v = *reinterpret_cast<const int4*>(p + pg1);
        return i32x8{u.x, u.y, u.z, u.w, v.x, v.y, v.z, v.w};
    };

    f32x16 acc00 = {}, acc01 = {}, acc10 = {}, acc11 = {};
    float rowacc0[16], rowacc1[16];
#pragma unroll
    for (int r = 0; r < 16; ++r) { rowacc0[r] = 0.f; rowacc1[r] = 0.f; }
    const int row0b = rb + wr * 64 + 4 * hi;
    const int cstrip = blockIdx.y * CPB;       // first col-block of this strip

    // prologue: stage tiles 0 and 1 (KITER=12 > 2, both in col-block 0)
    stage(cstrip * BNB, 0, 0);
    stage(cstrip * BNB, KBLK, 1);

    int ct = 0, kt = 0;                        // current tile coords
    int sct = 0, skt = 2;                      // tile it+2 coords
    int cur = 0, sbuf = 2;
    for (int it = 0; it < TOT; ++it) {
        if (it < TOT - 1) {
            asm volatile("s_waitcnt vmcnt(4)" ::: "memory");  // tile(it) landed
        } else {
            asm volatile("s_waitcnt vmcnt(0)" ::: "memory");
        }
        __builtin_amdgcn_s_barrier();          // all waves: buf ready, old reads done

        if (it + 2 < TOT) {
            stage((cstrip + sct) * BNB, skt * KBLK, sbuf);
            if (++skt == KITER) { skt = 0; ++sct; }
            sbuf = (sbuf == 2) ? 0 : sbuf + 1;
        }

        i32x8 a0 = ldf(&As[cur][raA]);
        i32x8 a1 = ldf(&As[cur][raB]);
        i32x8 b0 = ldf(&Bs[cur][caA]);
        i32x8 b1 = ldf(&Bs[cur][caB]);
        acc00 = __builtin_amdgcn_mfma_scale_f32_32x32x64_f8f6f4(a0, b0, acc00, 0, 0, 0, SC1, 0, SC1);
        acc01 = __builtin_amdgcn_mfma_scale_f32_32x32x64_f8f6f4(a0, b1, acc01, 0, 0, 0, SC1, 0, SC1);
        acc10 = __builtin_amdgcn_mfma_scale_f32_32x32x64_f8f6f4(a1, b0, acc10, 0, 0, 0, SC1, 0, SC1);
        acc11 = __builtin_amdgcn_mfma_scale_f32_32x32x64_f8f6f4(a1, b1, acc11, 0, 0, 0, SC1, 0, SC1);

        if (kt == KITER - 1) {
            // exp + mask + per-lane accumulate (no shuffles here)
            const int cblk = cstrip + ct;
            const bool on_diag = (cblk == bi);
            const int colg = cblk * BNB + wc * 64 + rlo;
#pragma unroll
            for (int r = 0; r < 16; ++r) {
                const int rg0 = row0b + (r & 3) + 8 * (r >> 2);
                float e00 = __expf((acc00[r] - 1.0f) * INV_T);
                float e01 = __expf((acc01[r] - 1.0f) * INV_T);
                float e10 = __expf((acc10[r] - 1.0f) * INV_T);
                float e11 = __expf((acc11[r] - 1.0f) * INV_T);
                if (on_diag) {
                    if (rg0 == colg)           e00 = 0.f;
                    if (rg0 == colg + 32)      e01 = 0.f;
                    if (rg0 + 32 == colg)      e10 = 0.f;
                    if (rg0 + 32 == colg + 32) e11 = 0.f;
                }
                rowacc0[r] += e00 + e01;
                rowacc1[r] += e10 + e11;
            }
            acc00 = f32x16{}; acc01 = f32x16{};
            acc10 = f32x16{}; acc11 = f32x16{};
        }
        if (++kt == KITER) { kt = 0; ++ct; }
        cur = (cur == 2) ? 0 : cur + 1;
    }

    // block end: ONE butterfly over 32 col-lanes + atomics
#pragma unroll
    for (int r = 0; r < 16; ++r) {
#pragma unroll
        for (int m = 1; m < 32; m <<= 1) {
            rowacc0[r] += __shfl_xor(rowacc0[r], m);
            rowacc1[r] += __shfl_xor(rowacc1[r], m);
        }
    }
    if (rlo == 0) {
#pragma unroll
        for (int r = 0; r < 16; ++r) {
            const int rg0 = row0b + (r & 3) + 8 * (r >> 2);
            atomicAdd(&rowsum[rg0], rowacc0[r]);
            atomicAdd(&rowsum[rg0 + 32], rowacc1[r]);
        }
    }
}

// ---------------- final: loss = mean(M + log S_i - pos) ---------------------
__global__ void kfinal(const float* __restrict__ rowsum, const float* __restrict__ pos,
                       float* __restrict__ out) {
    __shared__ float red[8];
    const int tid = threadIdx.x;
    float s = 0.f;
    for (int i = tid; i < N2; i += 512) {
        const int p = (i < NPAIR) ? i : i - NPAIR;
        s += INV_T + __logf(rowsum[i]) - pos[p];
    }
#pragma unroll
    for (int off = 32; off; off >>= 1) s += __shfl_xor(s, off);
    if ((tid & 63) == 0) red[tid >> 6] = s;
    __syncthreads();
    if (tid == 0) {
        float t = 0.f;
#pragma unroll
        for (int w = 0; w < 8; ++w) t += red[w];
        out[0] = t / (float)N2;
    }
}

extern "C" void kernel_launch(void* const* d_in, const int* in_sizes, int n_in,
                              void* d_out, int out_size, void* d_ws, size_t ws_size,
                              hipStream_t stream) {
    const float* z1 = (const float*)d_in[0];
    const float* z2 = (const float*)d_in[1];
    unsigned char* zq = (unsigned char*)d_ws;                         // 8192*768 fp8
    float* rowsum = (float*)((char*)d_ws + (size_t)N2 * DIM);         // 8192 f32
    float* pos = rowsum + N2;                                         // 4096 f32
    float* out = (float*)d_out;

    hipLaunchKernelGGL(knorm, dim3(N2 / 4), dim3(256), 0, stream, z1, z2, zq);
    hipLaunchKernelGGL(kpos, dim3(NPAIR / 4), dim3(256), 0, stream, zq, pos);
    hipMemsetAsync(rowsum, 0, N2 * sizeof(float), stream);
    hipLaunchKernelGGL(klse, dim3(NBI, NSTRIP), dim3(256), 0, stream, zq, rowsum);
    hipLaunchKernelGGL(kfinal, dim3(1), dim3(512), 0, stream, rowsum, pos, out);
}